// Round 12
// baseline (555.443 us; speedup 1.0000x reference)
//
#include <hip/hip_runtime.h>
#include <stdint.h>

typedef unsigned short ushort_t;
typedef __attribute__((ext_vector_type(4))) float f32x4;
typedef __attribute__((ext_vector_type(8))) short s16x8;

#define DEVFN static __device__ __forceinline__

constexpr int B_   = 1024;
constexpr int P_   = 93528;   // upper-tri pairs of 432
constexpr int K1   = 93544;   // 16 + P_
constexpr int Kp   = 94208;   // padded K: 16 splits * 92 steps * 64
constexpr int SPLITS = 16;
constexpr int KCH  = Kp / SPLITS;  // 5888
constexpr int KSTEPS = KCH / 64;   // 92
// xT layout: [434][1024]; row 432 = ones, row 433 = zeros (branch-free products)
// Z layout:  blocked [(k/8)][m][8] bf16
// WT layout: blocked [(k/8)][n][8] bf16  (same as Z -> B staging == A staging)

DEVFN ushort_t f2bf(float f) {
  union { float f; unsigned int u; } x; x.f = f;
  unsigned int r = x.u + 0x7FFFu + ((x.u >> 16) & 1u);
  return (ushort_t)(r >> 16);
}

DEVFN void gload_lds16(const void* g, void* l) {
  __builtin_amdgcn_global_load_lds((const __attribute__((address_space(1))) unsigned int*)g,
                                   (__attribute__((address_space(3))) unsigned int*)l, 16, 0, 0);
}

// ---------- fused pre-pass: iu table + xT pad rows | bottom MLP | embedding ----------
// grid: [0,368) iu, [368,432) bot, [432,536) emb
__global__ __launch_bounds__(256) void k_pre(const float* __restrict__ dense,
    const int* __restrict__ sparse, const float* __restrict__ tbl,
    const float* __restrict__ bw0, const float* __restrict__ bb0,
    const float* __restrict__ bw1, const float* __restrict__ bb1,
    const float* __restrict__ bw2, const float* __restrict__ bb2,
    const float* __restrict__ bw3, const float* __restrict__ bb3,
    int* __restrict__ iu, float* __restrict__ xT) {
  __shared__ float sm[13520];   // bot: xs 208 | h1 8192 | h2 4096 | h3 1024
  int bid = blockIdx.x, t = threadIdx.x;
  if (bid < 368) {
    // ---- iu + pad ----
    int k = bid * 256 + t;
    if (bid < 8) {
      int idx = bid * 256 + t;
      xT[432 * 1024 + idx] = (idx < 1024) ? 1.f : 0.f;
    }
    if (k >= Kp) return;
    int v;
    if (k < 16) v = k | (432 << 16);
    else if (k >= K1) v = 433 | (433 << 16);
    else {
      int p = k - 16;
      float s = sqrtf((float)(748225 - 8 * p));      // 865^2
      int i = (int)((865.0f - s) * 0.5f);
      if (i < 0) i = 0; if (i > 431) i = 431;
      while (i < 431 && (i + 1) * (865 - (i + 1)) / 2 <= p) ++i;
      while (i > 0 && i * (865 - i) / 2 > p) --i;
      int j = i + (p - i * (865 - i) / 2);
      v = i | (j << 16);
    }
    iu[k] = v;
  } else if (bid < 432) {
    // ---- bottom MLP: 13->512->256->64->16, 16 rows/block ----
    float* xs = sm;
    float* h1 = sm + 208;
    float* h2 = h1 + 8192;
    float* h3 = h2 + 4096;
    int m0 = (bid - 368) * 16;
    if (t < 208) xs[t] = dense[m0 * 13 + t];
    __syncthreads();
    #pragma unroll
    for (int h = 0; h < 2; ++h) {
      int n = h * 256 + t;
      float a[16];
      float bv = bb0[n];
      #pragma unroll
      for (int r = 0; r < 16; ++r) a[r] = bv;
      for (int k = 0; k < 13; ++k) {
        float w = bw0[k * 512 + n];
        #pragma unroll
        for (int r = 0; r < 16; ++r) a[r] = fmaf(xs[r * 13 + k], w, a[r]);
      }
      #pragma unroll
      for (int r = 0; r < 16; ++r) h1[r * 512 + n] = fmaxf(a[r], 0.f);
    }
    __syncthreads();
    {
      int n = t;
      float a[16];
      float bv = bb1[n];
      #pragma unroll
      for (int r = 0; r < 16; ++r) a[r] = bv;
      for (int k = 0; k < 512; ++k) {
        float w = bw1[k * 256 + n];
        #pragma unroll
        for (int r = 0; r < 16; ++r) a[r] = fmaf(h1[r * 512 + k], w, a[r]);
      }
      #pragma unroll
      for (int r = 0; r < 16; ++r) h2[r * 256 + n] = fmaxf(a[r], 0.f);
    }
    __syncthreads();
    {
      int n = t & 63, r0 = t >> 6;
      float a[4];
      float bv = bb2[n];
      #pragma unroll
      for (int i = 0; i < 4; ++i) a[i] = bv;
      for (int k = 0; k < 256; ++k) {
        float w = bw2[k * 64 + n];
        #pragma unroll
        for (int i = 0; i < 4; ++i) a[i] = fmaf(h2[(r0 + 4 * i) * 256 + k], w, a[i]);
      }
      #pragma unroll
      for (int i = 0; i < 4; ++i) h3[(r0 + 4 * i) * 64 + n] = fmaxf(a[i], 0.f);
    }
    __syncthreads();
    {
      int n = t & 15, r = t >> 4;
      float a = bb3[n];
      for (int k = 0; k < 64; ++k) a = fmaf(h3[r * 64 + k], bw3[k * 16 + n], a);
      xT[(size_t)n * B_ + m0 + r] = fmaxf(a, 0.f);
    }
  } else {
    // ---- embedding gather into xT rows 16..431 ----
    int e = bid - 432;
    int f = e >> 2;
    int b = (e & 3) * 256 + t;
    int idx = sparse[(size_t)b * 26 + f];
    const float4* src = (const float4*)(tbl + ((size_t)f * 100000 + idx) * 16);
    #pragma unroll
    for (int q = 0; q < 4; ++q) {
      float4 v = src[q];
      int r = 16 + f * 16 + q * 4;
      xT[(size_t)(r + 0) * B_ + b] = v.x;
      xT[(size_t)(r + 1) * B_ + b] = v.y;
      xT[(size_t)(r + 2) * B_ + b] = v.z;
      xT[(size_t)(r + 3) * B_ + b] = v.w;
    }
  }
}

// ---------- fused Z-gen + W-convert, 2-deep software-pipelined (R11: VGPR=24 serial) ----------
// grid 8832; bid%3==0 -> genz (2944 blocks), else -> wt (5888 blocks)
// Named register sets (pA/pB, vA/vB) keep 16 loads in flight per thread; the
// compiler's dependency waitcnt then drains only the consumed set.
__global__ __launch_bounds__(256, 8) void k_gz(const float* __restrict__ xT,
                                               const int* __restrict__ iu,
                                               const float* __restrict__ tw0,
                                               ushort_t* __restrict__ Z,
                                               ushort_t* __restrict__ WT) {
  __shared__ int ls_iu[512];
  int bid = blockIdx.x, t = threadIdx.x;
  int r3 = bid % 3;
  if (r3 == 0) {
    // ---- Z generation: blocked layout Z[(k/8)][m][8] ----
    int idx = bid / 3;
    int l = t & 63, w = t >> 6;
    int mb = (idx & 15) * 64;
    int kt = (idx >> 4) * 512;
    ls_iu[t] = iu[kt + t];
    ls_iu[256 + t] = iu[kt + 256 + t];
    __syncthreads();
    uint32_t moff = mb + l;
    int kw = w * 128;

    auto ld_p = [&](float* p, int g) {
      int kloc = kw + g * 8;
      int4 ij0 = *(const int4*)&ls_iu[kloc];
      int4 ij1 = *(const int4*)&ls_iu[kloc + 4];
      int v0 = ij0.x, v1 = ij0.y, v2 = ij0.z, v3 = ij0.w;
      p[0] = xT[(uint32_t)((v0 & 0xFFFF) << 10) + moff] * xT[(uint32_t)((v0 >> 16) << 10) + moff];
      p[1] = xT[(uint32_t)((v1 & 0xFFFF) << 10) + moff] * xT[(uint32_t)((v1 >> 16) << 10) + moff];
      p[2] = xT[(uint32_t)((v2 & 0xFFFF) << 10) + moff] * xT[(uint32_t)((v2 >> 16) << 10) + moff];
      p[3] = xT[(uint32_t)((v3 & 0xFFFF) << 10) + moff] * xT[(uint32_t)((v3 >> 16) << 10) + moff];
      v0 = ij1.x; v1 = ij1.y; v2 = ij1.z; v3 = ij1.w;
      p[4] = xT[(uint32_t)((v0 & 0xFFFF) << 10) + moff] * xT[(uint32_t)((v0 >> 16) << 10) + moff];
      p[5] = xT[(uint32_t)((v1 & 0xFFFF) << 10) + moff] * xT[(uint32_t)((v1 >> 16) << 10) + moff];
      p[6] = xT[(uint32_t)((v2 & 0xFFFF) << 10) + moff] * xT[(uint32_t)((v2 >> 16) << 10) + moff];
      p[7] = xT[(uint32_t)((v3 & 0xFFFF) << 10) + moff] * xT[(uint32_t)((v3 >> 16) << 10) + moff];
    };
    auto st_p = [&](const float* p, int g) {
      union { uint32_t w4[4]; int4 v4; } o;
      asm("v_cvt_pk_bf16_f32 %0, %1, %2" : "=v"(o.w4[0]) : "v"(p[0]), "v"(p[1]));
      asm("v_cvt_pk_bf16_f32 %0, %1, %2" : "=v"(o.w4[1]) : "v"(p[2]), "v"(p[3]));
      asm("v_cvt_pk_bf16_f32 %0, %1, %2" : "=v"(o.w4[2]) : "v"(p[4]), "v"(p[5]));
      asm("v_cvt_pk_bf16_f32 %0, %1, %2" : "=v"(o.w4[3]) : "v"(p[6]), "v"(p[7]));
      int kglob = kt + kw + g * 8;
      *(int4*)&Z[((size_t)(kglob >> 3) * 1024 + moff) * 8] = o.v4;
    };

    float pA[8], pB[8];
    ld_p(pA, 0);
    #pragma unroll
    for (int pr = 0; pr < 8; ++pr) {
      ld_p(pB, 2 * pr + 1);
      st_p(pA, 2 * pr);
      if (2 * pr + 2 < 16) ld_p(pA, 2 * pr + 2);
      st_p(pB, 2 * pr + 1);
    }
  } else {
    // ---- WT: tw0 (K1 x 1024 f32) -> blocked WT[(k/8)][n][8] bf16, transpose-free ----
    int idx = (bid / 3) * 2 + r3 - 1;          // 0..5887
    int k0 = (idx % 368) * 256, n0 = (idx / 368) * 64;
    int nl = t & 63, kq = t >> 6;
    int n = n0 + nl;
    int kbase = k0 + kq * 64;
    const float* src = tw0 + (size_t)kbase * 1024 + n;
    ushort_t* dst = WT + ((size_t)(kbase >> 3) * 1024 + n) * 8;

    auto ld_v = [&](float* v, int g) {
      int kg = kbase + g * 8;
      if (kg + 8 <= K1) {
        #pragma unroll
        for (int e = 0; e < 8; ++e) v[e] = src[(size_t)(g * 8 + e) << 10];
      } else {
        #pragma unroll
        for (int e = 0; e < 8; ++e) {
          int k = kg + e;
          v[e] = (k < K1) ? src[(size_t)(g * 8 + e) << 10] : 0.f;
        }
      }
    };
    auto st_v = [&](const float* v, int g) {
      union { uint32_t w4[4]; int4 v4; } o;
      asm("v_cvt_pk_bf16_f32 %0, %1, %2" : "=v"(o.w4[0]) : "v"(v[0]), "v"(v[1]));
      asm("v_cvt_pk_bf16_f32 %0, %1, %2" : "=v"(o.w4[1]) : "v"(v[2]), "v"(v[3]));
      asm("v_cvt_pk_bf16_f32 %0, %1, %2" : "=v"(o.w4[2]) : "v"(v[4]), "v"(v[5]));
      asm("v_cvt_pk_bf16_f32 %0, %1, %2" : "=v"(o.w4[3]) : "v"(v[6]), "v"(v[7]));
      *(int4*)(dst + (size_t)g * 8192) = o.v4;   // next k-chunk: +1024 rows * 8
    };

    float vA[8], vB[8];
    ld_v(vA, 0);
    #pragma unroll
    for (int pr = 0; pr < 4; ++pr) {
      ld_v(vB, 2 * pr + 1);
      st_v(vA, 2 * pr);
      if (2 * pr + 2 < 8) ld_v(vA, 2 * pr + 2);
      st_v(vB, 2 * pr + 1);
    }
  }
}

// ---------- main bf16 GEMM: m201-style 8-phase schedule + XCD-local split mapping ----------
// (frozen this round — see R11 notes; tail-drain fix verified)
__global__ __launch_bounds__(512, 2) void k_gemm(const ushort_t* __restrict__ Z,
                                                 const ushort_t* __restrict__ WT,
                                                 float* __restrict__ part) {
  __shared__ ushort_t lds[65536];   // A: [2][16384] at 0; B: [2][16384] at 32768 (128 KB)
  int t = threadIdx.x;
  int bid = blockIdx.x;
  int x = bid & 7, r = bid >> 3;
  int g = (x << 3) | (r & 7);            // (split, m-tile) index in [0,64)
  int s = g >> 2;
  int m0 = (g & 3) * 256, n0 = (r >> 3) * 256;
  int kb = s * KCH;

  int rr = t >> 3, cc = t & 7;
  int cs = cc ^ (rr & 7);                          // inverse swizzle on global source
  const ushort_t* pa0 = Z  + (((size_t)(kb >> 3) + cs) * 1024 + m0 + rr) * 8;
  const ushort_t* pb0 = WT + (((size_t)(kb >> 3) + cs) * 1024 + n0 + rr) * 8;
  int l0 = t * 8;

  int w = t >> 6, l = t & 63;
  int wm = (w >> 2) * 128, wn = (w & 3) * 64;
  int lhi = l >> 4, llo = l & 15;

  f32x4 acc[8][4];
  #pragma unroll
  for (int a = 0; a < 8; ++a)
    #pragma unroll
    for (int b = 0; b < 4; ++b) acc[a][b] = f32x4{0.f, 0.f, 0.f, 0.f};

  s16x8 bf[4][2], afX[4], afY[4];

  auto rdA = [&](s16x8* dst, int mfb, const ushort_t* Ab) {
    #pragma unroll
    for (int j = 0; j < 2; ++j)
      #pragma unroll
      for (int ks = 0; ks < 2; ++ks) {
        int row = wm + (mfb + j) * 16 + llo;
        int ch = (ks * 4 + lhi) ^ (row & 7);
        dst[j * 2 + ks] = *(const s16x8*)&Ab[row * 64 + ch * 8];
      }
  };
  auto rdB = [&](const ushort_t* Bb) {
    #pragma unroll
    for (int nf = 0; nf < 4; ++nf)
      #pragma unroll
      for (int ks = 0; ks < 2; ++ks) {
        int row = wn + nf * 16 + llo;
        int ch = (ks * 4 + lhi) ^ (row & 7);
        bf[nf][ks] = *(const s16x8*)&Bb[row * 64 + ch * 8];
      }
  };

#define MFMA_PHASE(P, AF)                                                        \
  __builtin_amdgcn_s_barrier();                                                  \
  asm volatile("s_waitcnt lgkmcnt(0)" ::: "memory");                             \
  __builtin_amdgcn_sched_barrier(0);                                             \
  __builtin_amdgcn_s_setprio(1);                                                 \
  _Pragma("unroll")                                                              \
  for (int j = 0; j < 2; ++j)                                                    \
    _Pragma("unroll")                                                            \
    for (int nf = 0; nf < 4; ++nf)                                               \
      _Pragma("unroll")                                                          \
      for (int ks = 0; ks < 2; ++ks)                                             \
        acc[(P) * 2 + j][nf] = __builtin_amdgcn_mfma_f32_16x16x32_bf16(          \
            AF[j * 2 + ks], bf[nf][ks], acc[(P) * 2 + j][nf], 0, 0, 0);          \
  __builtin_amdgcn_s_setprio(0);                                                 \
  __builtin_amdgcn_sched_barrier(0);                                             \
  __builtin_amdgcn_s_barrier();

  // ---- prologue: stage A[0], B[0], B[1]; wait A0+B0; preload afX(mf01 of A[0]) ----
  #pragma unroll
  for (int i = 0; i < 4; ++i) gload_lds16(pa0 + i * 512, &lds[i * 4096 + l0]);
  #pragma unroll
  for (int i = 0; i < 4; ++i) gload_lds16(pb0 + i * 512, &lds[32768 + i * 4096 + l0]);
  #pragma unroll
  for (int i = 0; i < 4; ++i) gload_lds16(pb0 + 65536 + i * 512, &lds[32768 + 16384 + i * 4096 + l0]);
  asm volatile("s_waitcnt vmcnt(4)" ::: "memory");   // A[0], B[0] complete; B[1] in flight
  __builtin_amdgcn_s_barrier();
  rdA(afX, 0, &lds[0]);

  for (int tt = 0; tt < KSTEPS; ++tt) {
    const ushort_t* Ab = &lds[(tt & 1) * 16384];
    const ushort_t* An = &lds[((tt + 1) & 1) * 16384];
    const ushort_t* Bb = &lds[32768 + (tt & 1) * 16384];
    ushort_t* dA  = &lds[((tt + 1) & 1) * 16384];
    ushort_t* dB2 = &lds[32768 + (tt & 1) * 16384];       // B[tt+2] parity == tt
    const ushort_t* sA  = pa0 + (size_t)(tt + 1) * 65536;
    const ushort_t* sB2 = pb0 + (size_t)(tt + 2) * 65536;
    bool pf1 = (tt + 1 < KSTEPS);
    bool pf2 = (tt + 2 < KSTEPS);

    // ---- p0: reads bf(B[tt]) + afY=mf23; issues A[tt+1] g0,g1; MFMA mf01(afX)
    rdB(Bb);
    rdA(afY, 2, Ab);
    if (pf1) {
      gload_lds16(sA,       dA + l0);
      gload_lds16(sA + 512, dA + 4096 + l0);
    }
    MFMA_PHASE(0, afX)

    // ---- p1: reads afX=mf45; issues A[tt+1] g2,g3; MFMA mf23(afY)
    rdA(afX, 4, Ab);
    if (pf1) {
      gload_lds16(sA + 1024, dA + 2 * 4096 + l0);
      gload_lds16(sA + 1536, dA + 3 * 4096 + l0);
    }
    MFMA_PHASE(1, afY)

    // ---- p2: reads afY=mf67; issues B[tt+2] g0,g1; MFMA mf45(afX)
    rdA(afY, 6, Ab);
    if (pf2) {
      gload_lds16(sB2,       dB2 + l0);
      gload_lds16(sB2 + 512, dB2 + 4096 + l0);
    }
    MFMA_PHASE(2, afX)

    // ---- p3: wait A[tt+1] ready; reads afX=mf01(A[tt+1]); issues B[tt+2] g2,g3; MFMA mf67(afY)
    if (pf1) {
      if (pf2) asm volatile("s_waitcnt vmcnt(2)" ::: "memory");  // leaves B[tt+2]g0,g1
      else     asm volatile("s_waitcnt vmcnt(0)" ::: "memory");  // TAIL: full drain (R10 fix)
      rdA(afX, 0, An);
    }
    if (pf2) {
      gload_lds16(sB2 + 1024, dB2 + 2 * 4096 + l0);
      gload_lds16(sB2 + 1536, dB2 + 3 * 4096 + l0);
    }
    MFMA_PHASE(3, afY)
  }
#undef MFMA_PHASE

  float* pbase = part + ((size_t)s << 20);
  #pragma unroll
  for (int mf = 0; mf < 8; ++mf)
    #pragma unroll
    for (int nf = 0; nf < 4; ++nf) {
      int n = n0 + wn + nf * 16 + llo;
      #pragma unroll
      for (int r2 = 0; r2 < 4; ++r2) {
        int m = m0 + wm + mf * 16 + lhi * 4 + r2; // C layout: col=lane&15, row=(lane>>4)*4+reg
        pbase[(size_t)m * 1024 + n] = acc[mf][nf][r2];
      }
    }
}

// ---------- reduce partials + bias + relu -> z1 ----------
__global__ __launch_bounds__(256) void k_red(const float* __restrict__ part,
                                             const float* __restrict__ bias,
                                             float* __restrict__ z1) {
  int idx = blockIdx.x * 256 + threadIdx.x;
  float a = bias[idx & 1023];
  #pragma unroll
  for (int s = 0; s < SPLITS; ++s) a += part[((size_t)s << 20) + idx];
  z1[idx] = fmaxf(a, 0.f);
}

// ---------- tiled fp32 SGEMM for top MLP: C=relu(A@W+b), 32x64 tile ----------
template<int K, int N>
__global__ __launch_bounds__(256) void k_sgemm(const float* __restrict__ A,
                                               const float* __restrict__ W,
                                               const float* __restrict__ bias,
                                               float* __restrict__ C) {
  __shared__ float As[16][34];
  __shared__ float Bs[16][68];
  int t = threadIdx.x;
  int m0 = blockIdx.x * 32, n0 = blockIdx.y * 64;
  int tx = t & 15, ty = t >> 4;
  float acc[2][4];
  #pragma unroll
  for (int j = 0; j < 2; ++j)
    #pragma unroll
    for (int q = 0; q < 4; ++q) acc[j][q] = 0.f;
  int ar = t >> 3, ak = (t & 7) * 2;
  int bk = t >> 4, bn = (t & 15) * 4;
  for (int k0 = 0; k0 < K; k0 += 16) {
    float2 av = *(const float2*)&A[(size_t)(m0 + ar) * K + k0 + ak];
    float4 bv = *(const float4*)&W[(size_t)(k0 + bk) * N + n0 + bn];
    __syncthreads();
    As[ak][ar] = av.x; As[ak + 1][ar] = av.y;
    *(float4*)&Bs[bk][bn] = bv;
    __syncthreads();
    #pragma unroll
    for (int k = 0; k < 16; ++k) {
      float2 a = *(const float2*)&As[k][ty * 2];
      float4 b = *(const float4*)&Bs[k][tx * 4];
      acc[0][0] = fmaf(a.x, b.x, acc[0][0]); acc[0][1] = fmaf(a.x, b.y, acc[0][1]);
      acc[0][2] = fmaf(a.x, b.z, acc[0][2]); acc[0][3] = fmaf(a.x, b.w, acc[0][3]);
      acc[1][0] = fmaf(a.y, b.x, acc[1][0]); acc[1][1] = fmaf(a.y, b.y, acc[1][1]);
      acc[1][2] = fmaf(a.y, b.z, acc[1][2]); acc[1][3] = fmaf(a.y, b.w, acc[1][3]);
    }
  }
  #pragma unroll
  for (int j = 0; j < 2; ++j) {
    int m = m0 + ty * 2 + j;
    float4 o;
    o.x = fmaxf(acc[j][0] + bias[n0 + tx * 4 + 0], 0.f);
    o.y = fmaxf(acc[j][1] + bias[n0 + tx * 4 + 1], 0.f);
    o.z = fmaxf(acc[j][2] + bias[n0 + tx * 4 + 2], 0.f);
    o.w = fmaxf(acc[j][3] + bias[n0 + tx * 4 + 3], 0.f);
    *(float4*)&C[(size_t)m * N + n0 + tx * 4] = o;
  }
}

// ---------- final layer: K=256 -> 1, wave reduction ----------
__global__ __launch_bounds__(256) void k_last(const float* __restrict__ z3,
                                              const float* __restrict__ w,
                                              const float* __restrict__ bias,
                                              float* __restrict__ out) {
  int t = threadIdx.x, l = t & 63, wv = t >> 6;
  int m = blockIdx.x * 4 + wv;
  float s = 0.f;
  #pragma unroll
  for (int c = 0; c < 4; ++c) s = fmaf(z3[(size_t)m * 256 + c * 64 + l], w[c * 64 + l], s);
  #pragma unroll
  for (int off = 32; off; off >>= 1) s += __shfl_down(s, off, 64);
  if (l == 0) out[m] = s + bias[0];
}

// ---------- fallback path (small workspace): fp32 fused-gen GEMM ----------
__global__ __launch_bounds__(256) void k_z1init(const float* __restrict__ bias, float* __restrict__ z1) {
  int idx = blockIdx.x * 256 + threadIdx.x;
  z1[idx] = bias[idx & 1023];
}
__global__ __launch_bounds__(256) void k_relu(float* __restrict__ z1) {
  int idx = blockIdx.x * 256 + threadIdx.x;
  z1[idx] = fmaxf(z1[idx], 0.f);
}
constexpr int FB_S = 8;
__global__ __launch_bounds__(256) void k_fbgemm(const float* __restrict__ xT,
                                                const int* __restrict__ iu,
                                                const float* __restrict__ tw0,
                                                float* __restrict__ z1) {
  __shared__ float zs[32 * 64];
  __shared__ float wsb[32 * 64];
  int t = threadIdx.x;
  int m0 = blockIdx.x * 64, n0 = blockIdx.y * 64, s = blockIdx.z;
  int kch = (K1 + FB_S - 1) / FB_S;
  int k0 = s * kch, kend = min(k0 + kch, K1);
  float acc[16];
  #pragma unroll
  for (int q = 0; q < 16; ++q) acc[q] = 0.f;
  int mm = t & 63, ng = t >> 6;
  for (int kk = k0; kk < kend; kk += 32) {
    __syncthreads();
    for (int sl = t; sl < 2048; sl += 256) {
      int kloc = sl >> 6, v6 = sl & 63;
      int k = kk + kloc;
      float zv = 0.f, wv = 0.f;
      if (k < kend) {
        int ij = iu[k];
        int i = ij & 0xFFFF, j = ij >> 16;
        zv = xT[(size_t)i * B_ + m0 + v6] * xT[(size_t)j * B_ + m0 + v6];
        wv = tw0[(size_t)k * 1024 + n0 + v6];
      }
      zs[kloc * 64 + v6] = zv;
      wsb[kloc * 64 + v6] = wv;
    }
    __syncthreads();
    #pragma unroll 4
    for (int kloc = 0; kloc < 32; ++kloc) {
      float zv = zs[kloc * 64 + mm];
      #pragma unroll
      for (int q = 0; q < 16; ++q)
        acc[q] = fmaf(zv, wsb[kloc * 64 + ng * 16 + q], acc[q]);
    }
  }
  #pragma unroll
  for (int q = 0; q < 16; ++q)
    atomicAdd(&z1[(size_t)(m0 + mm) * 1024 + n0 + ng * 16 + q], acc[q]);
}

extern "C" void kernel_launch(void* const* d_in, const int* in_sizes, int n_in,
                              void* d_out, int out_size, void* d_ws, size_t ws_size,
                              hipStream_t stream) {
  const float* dense  = (const float*)d_in[0];
  const int*   sparse = (const int*)  d_in[1];
  const float* emb    = (const float*)d_in[2];
  const float* bw0 = (const float*)d_in[3];  const float* bb0 = (const float*)d_in[4];
  const float* bw1 = (const float*)d_in[5];  const float* bb1 = (const float*)d_in[6];
  const float* bw2 = (const float*)d_in[7];  const float* bb2 = (const float*)d_in[8];
  const float* bw3 = (const float*)d_in[9];  const float* bb3 = (const float*)d_in[10];
  const float* tw0 = (const float*)d_in[11]; const float* tb0 = (const float*)d_in[12];
  const float* tw1 = (const float*)d_in[13]; const float* tb1 = (const float*)d_in[14];
  const float* tw2 = (const float*)d_in[15]; const float* tb2 = (const float*)d_in[16];
  const float* tw3 = (const float*)d_in[17]; const float* tb3 = (const float*)d_in[18];
  float* out = (float*)d_out;

  char* ws = (char*)d_ws;
  size_t off = 0;
  auto alloc = [&](size_t bytes) -> char* {
    char* p = ws + off;
    off = (off + bytes + 255) & ~(size_t)255;
    return p;
  };
  float* xT = (float*)alloc((size_t)434 * 1024 * 4);
  int*   iu = (int*)  alloc((size_t)Kp * 4);
  float* z1 = (float*)alloc((size_t)1024 * 1024 * 4);
  float* z2 = (float*)alloc((size_t)1024 * 512 * 4);
  float* z3 = (float*)alloc((size_t)1024 * 256 * 4);
  ushort_t* Z    = (ushort_t*)alloc((size_t)1024 * Kp * 2);
  ushort_t* WT   = (ushort_t*)alloc((size_t)1024 * Kp * 2);
  float*    part = (float*)   alloc((size_t)SPLITS * 1024 * 1024 * 4);
  bool big = (off <= ws_size);

  k_pre<<<536, 256, 0, stream>>>(dense, sparse, emb, bw0, bb0, bw1, bb1, bw2, bb2, bw3, bb3, iu, xT);

  if (big) {
    k_gz<<<8832, 256, 0, stream>>>(xT, iu, tw0, Z, WT);
    k_gemm<<<256, 512, 0, stream>>>(Z, WT, part);
    k_red<<<4096, 256, 0, stream>>>(part, tb0, z1);
  } else {
    k_z1init<<<4096, 256, 0, stream>>>(tb0, z1);
    k_fbgemm<<<dim3(16, 16, FB_S), 256, 0, stream>>>(xT, iu, tw0, z1);
    k_relu<<<4096, 256, 0, stream>>>(z1);
  }

  k_sgemm<1024, 512><<<dim3(32, 8), 256, 0, stream>>>(z1, tw1, tb1, z2);
  k_sgemm<512, 256><<<dim3(32, 4), 256, 0, stream>>>(z2, tw2, tb2, z3);
  k_last<<<256, 256, 0, stream>>>(z3, tw3, tb3, out);
}

// Round 13
// 479.237 us; speedup vs baseline: 1.1590x; 1.1590x over previous
//
#include <hip/hip_runtime.h>
#include <stdint.h>

typedef unsigned short ushort_t;
typedef __attribute__((ext_vector_type(4))) float f32x4;
typedef __attribute__((ext_vector_type(8))) short s16x8;

#define DEVFN static __device__ __forceinline__

constexpr int B_   = 1024;
constexpr int P_   = 93528;   // upper-tri pairs of 432
constexpr int K1   = 93544;   // 16 + P_
constexpr int Kp   = 94208;   // padded K: 16 splits * 92 steps * 64
constexpr int SPLITS = 16;
constexpr int KCH  = Kp / SPLITS;  // 5888
constexpr int KSTEPS = KCH / 64;   // 92
// xT layout: [434][1024]; row 432 = ones, row 433 = zeros (branch-free products)
// Z layout:  blocked [(k/8)][m][8] bf16
// WT layout: blocked [(k/8)][n][8] bf16  (same as Z -> B staging == A staging)

DEVFN ushort_t f2bf(float f) {
  union { float f; unsigned int u; } x; x.f = f;
  unsigned int r = x.u + 0x7FFFu + ((x.u >> 16) & 1u);
  return (ushort_t)(r >> 16);
}

DEVFN void gload_lds16(const void* g, void* l) {
  __builtin_amdgcn_global_load_lds((const __attribute__((address_space(1))) unsigned int*)g,
                                   (__attribute__((address_space(3))) unsigned int*)l, 16, 0, 0);
}

// ---------- fused pre-pass v2: bot MLP | iu+pad | embedding | WT-convert ----------
// grid (big path): [0,256) bot (4 rows/block), [256,624) iu, [624,728) emb,
// [728,6616) wt. Fallback path launches only 728 blocks (no wt -> no WT writes).
// wt depends only on tw0, so its BW work overlaps bot's latency chain.
__global__ __launch_bounds__(256) void k_pre(const float* __restrict__ dense,
    const int* __restrict__ sparse, const float* __restrict__ tbl,
    const float* __restrict__ bw0, const float* __restrict__ bb0,
    const float* __restrict__ bw1, const float* __restrict__ bb1,
    const float* __restrict__ bw2, const float* __restrict__ bb2,
    const float* __restrict__ bw3, const float* __restrict__ bb3,
    const float* __restrict__ tw0,
    int* __restrict__ iu, float* __restrict__ xT, ushort_t* __restrict__ WT) {
  __shared__ float sm[3392];   // bot: xs 64 | h1 2048 | h2 1024 | h3 256 (13.6 KB)
  int bid = blockIdx.x, t = threadIdx.x;
  if (bid < 256) {
    // ---- bottom MLP: 13->512->256->64->16, 4 rows/block ----
    float* xs = sm;
    float* h1 = sm + 64;
    float* h2 = h1 + 2048;
    float* h3 = h2 + 1024;
    int m0 = bid * 4;
    if (t < 52) xs[t] = dense[m0 * 13 + t];
    __syncthreads();
    #pragma unroll
    for (int h = 0; h < 2; ++h) {
      int n = h * 256 + t;
      float a[4];
      float bv = bb0[n];
      #pragma unroll
      for (int r = 0; r < 4; ++r) a[r] = bv;
      for (int k = 0; k < 13; ++k) {
        float w = bw0[k * 512 + n];
        #pragma unroll
        for (int r = 0; r < 4; ++r) a[r] = fmaf(xs[r * 13 + k], w, a[r]);
      }
      #pragma unroll
      for (int r = 0; r < 4; ++r) h1[r * 512 + n] = fmaxf(a[r], 0.f);
    }
    __syncthreads();
    {
      int n = t;
      float a[4];
      float bv = bb1[n];
      #pragma unroll
      for (int r = 0; r < 4; ++r) a[r] = bv;
      #pragma unroll 8
      for (int k = 0; k < 512; ++k) {
        float w = bw1[k * 256 + n];
        #pragma unroll
        for (int r = 0; r < 4; ++r) a[r] = fmaf(h1[r * 512 + k], w, a[r]);
      }
      #pragma unroll
      for (int r = 0; r < 4; ++r) h2[r * 256 + n] = fmaxf(a[r], 0.f);
    }
    __syncthreads();
    {
      int n = t & 63, r = t >> 6;
      float a = bb2[n];
      #pragma unroll 8
      for (int k = 0; k < 256; ++k) a = fmaf(h2[r * 256 + k], bw2[k * 64 + n], a);
      h3[r * 64 + n] = fmaxf(a, 0.f);
    }
    __syncthreads();
    if (t < 64) {
      int n = t & 15, r = t >> 4;
      float a = bb3[n];
      #pragma unroll 8
      for (int k = 0; k < 64; ++k) a = fmaf(h3[r * 64 + k], bw3[k * 16 + n], a);
      xT[(size_t)n * B_ + m0 + r] = fmaxf(a, 0.f);
    }
  } else if (bid < 624) {
    // ---- iu + xT pad rows ----
    int bb = bid - 256;
    int k = bb * 256 + t;
    if (bb < 8) {
      int idx = bb * 256 + t;
      xT[432 * 1024 + idx] = (idx < 1024) ? 1.f : 0.f;
    }
    if (k >= Kp) return;
    int v;
    if (k < 16) v = k | (432 << 16);
    else if (k >= K1) v = 433 | (433 << 16);
    else {
      int p = k - 16;
      float s = sqrtf((float)(748225 - 8 * p));      // 865^2
      int i = (int)((865.0f - s) * 0.5f);
      if (i < 0) i = 0; if (i > 431) i = 431;
      while (i < 431 && (i + 1) * (865 - (i + 1)) / 2 <= p) ++i;
      while (i > 0 && i * (865 - i) / 2 > p) --i;
      int j = i + (p - i * (865 - i) / 2);
      v = i | (j << 16);
    }
    iu[k] = v;
  } else if (bid < 728) {
    // ---- embedding gather into xT rows 16..431 ----
    int e = bid - 624;
    int f = e >> 2;
    int b = (e & 3) * 256 + t;
    int idx = sparse[(size_t)b * 26 + f];
    const float4* src = (const float4*)(tbl + ((size_t)f * 100000 + idx) * 16);
    #pragma unroll
    for (int q = 0; q < 4; ++q) {
      float4 v = src[q];
      int r = 16 + f * 16 + q * 4;
      xT[(size_t)(r + 0) * B_ + b] = v.x;
      xT[(size_t)(r + 1) * B_ + b] = v.y;
      xT[(size_t)(r + 2) * B_ + b] = v.z;
      xT[(size_t)(r + 3) * B_ + b] = v.w;
    }
  } else {
    // ---- WT: tw0 (K1 x 1024 f32) -> blocked WT[(k/8)][n][8] bf16, transpose-free ----
    int idx = bid - 728;                       // 0..5887
    int k0 = (idx % 368) * 256, n0 = (idx / 368) * 64;
    int nl = t & 63, kq = t >> 6;
    int n = n0 + nl;
    int kbase = k0 + kq * 64;
    const float* src = tw0 + (size_t)kbase * 1024 + n;
    ushort_t* dst = WT + ((size_t)(kbase >> 3) * 1024 + n) * 8;
    bool full = (kbase + 64 <= K1);
    #pragma unroll
    for (int g = 0; g < 8; ++g) {
      float v[8];
      if (full) {
        #pragma unroll
        for (int e = 0; e < 8; ++e) v[e] = src[(size_t)(g * 8 + e) << 10];
      } else {
        #pragma unroll
        for (int e = 0; e < 8; ++e) {
          int k = kbase + g * 8 + e;
          v[e] = (k < K1) ? src[(size_t)(g * 8 + e) << 10] : 0.f;
        }
      }
      union { uint32_t w4[4]; int4 v4; } o;
      asm("v_cvt_pk_bf16_f32 %0, %1, %2" : "=v"(o.w4[0]) : "v"(v[0]), "v"(v[1]));
      asm("v_cvt_pk_bf16_f32 %0, %1, %2" : "=v"(o.w4[1]) : "v"(v[2]), "v"(v[3]));
      asm("v_cvt_pk_bf16_f32 %0, %1, %2" : "=v"(o.w4[2]) : "v"(v[4]), "v"(v[5]));
      asm("v_cvt_pk_bf16_f32 %0, %1, %2" : "=v"(o.w4[3]) : "v"(v[6]), "v"(v[7]));
      *(int4*)(dst + (size_t)g * 8192) = o.v4;   // next k-chunk: +1024 rows * 8
    }
  }
}

// ---------- Z generation: blocked layout Z[(k/8)][m][8], grid 2944 ----------
__global__ __launch_bounds__(256, 8) void k_genz(const float* __restrict__ xT,
                                                 const int* __restrict__ iu,
                                                 ushort_t* __restrict__ Z) {
  __shared__ int ls_iu[512];
  int idx = blockIdx.x, t = threadIdx.x;
  int l = t & 63, w = t >> 6;
  int mb = (idx & 15) * 64;
  int kt = (idx >> 4) * 512;
  ls_iu[t] = iu[kt + t];
  ls_iu[256 + t] = iu[kt + 256 + t];
  __syncthreads();
  uint32_t moff = mb + l;
  int kw = w * 128;
  #pragma unroll 2
  for (int g = 0; g < 16; ++g) {
    int kloc = kw + g * 8;
    int4 ij0 = *(const int4*)&ls_iu[kloc];
    int4 ij1 = *(const int4*)&ls_iu[kloc + 4];
    float p[8];
    {
      int v0 = ij0.x, v1 = ij0.y, v2 = ij0.z, v3 = ij0.w;
      p[0] = xT[(uint32_t)((v0 & 0xFFFF) << 10) + moff] * xT[(uint32_t)((v0 >> 16) << 10) + moff];
      p[1] = xT[(uint32_t)((v1 & 0xFFFF) << 10) + moff] * xT[(uint32_t)((v1 >> 16) << 10) + moff];
      p[2] = xT[(uint32_t)((v2 & 0xFFFF) << 10) + moff] * xT[(uint32_t)((v2 >> 16) << 10) + moff];
      p[3] = xT[(uint32_t)((v3 & 0xFFFF) << 10) + moff] * xT[(uint32_t)((v3 >> 16) << 10) + moff];
      v0 = ij1.x; v1 = ij1.y; v2 = ij1.z; v3 = ij1.w;
      p[4] = xT[(uint32_t)((v0 & 0xFFFF) << 10) + moff] * xT[(uint32_t)((v0 >> 16) << 10) + moff];
      p[5] = xT[(uint32_t)((v1 & 0xFFFF) << 10) + moff] * xT[(uint32_t)((v1 >> 16) << 10) + moff];
      p[6] = xT[(uint32_t)((v2 & 0xFFFF) << 10) + moff] * xT[(uint32_t)((v2 >> 16) << 10) + moff];
      p[7] = xT[(uint32_t)((v3 & 0xFFFF) << 10) + moff] * xT[(uint32_t)((v3 >> 16) << 10) + moff];
    }
    union { uint32_t w4[4]; int4 v4; } o;
    asm("v_cvt_pk_bf16_f32 %0, %1, %2" : "=v"(o.w4[0]) : "v"(p[0]), "v"(p[1]));
    asm("v_cvt_pk_bf16_f32 %0, %1, %2" : "=v"(o.w4[1]) : "v"(p[2]), "v"(p[3]));
    asm("v_cvt_pk_bf16_f32 %0, %1, %2" : "=v"(o.w4[2]) : "v"(p[4]), "v"(p[5]));
    asm("v_cvt_pk_bf16_f32 %0, %1, %2" : "=v"(o.w4[3]) : "v"(p[6]), "v"(p[7]));
    int kglob = kt + kloc;
    *(int4*)&Z[((size_t)(kglob >> 3) * 1024 + moff) * 8] = o.v4;
  }
}

// ---------- main bf16 GEMM: m201-style 8-phase schedule + XCD-local split mapping ----------
// (frozen — verified R11/R12; tail-drain ledger fix in place)
__global__ __launch_bounds__(512, 2) void k_gemm(const ushort_t* __restrict__ Z,
                                                 const ushort_t* __restrict__ WT,
                                                 float* __restrict__ part) {
  __shared__ ushort_t lds[65536];   // A: [2][16384] at 0; B: [2][16384] at 32768 (128 KB)
  int t = threadIdx.x;
  int bid = blockIdx.x;
  int x = bid & 7, r = bid >> 3;
  int g = (x << 3) | (r & 7);            // (split, m-tile) index in [0,64)
  int s = g >> 2;
  int m0 = (g & 3) * 256, n0 = (r >> 3) * 256;
  int kb = s * KCH;

  int rr = t >> 3, cc = t & 7;
  int cs = cc ^ (rr & 7);                          // inverse swizzle on global source
  const ushort_t* pa0 = Z  + (((size_t)(kb >> 3) + cs) * 1024 + m0 + rr) * 8;
  const ushort_t* pb0 = WT + (((size_t)(kb >> 3) + cs) * 1024 + n0 + rr) * 8;
  int l0 = t * 8;

  int w = t >> 6, l = t & 63;
  int wm = (w >> 2) * 128, wn = (w & 3) * 64;
  int lhi = l >> 4, llo = l & 15;

  f32x4 acc[8][4];
  #pragma unroll
  for (int a = 0; a < 8; ++a)
    #pragma unroll
    for (int b = 0; b < 4; ++b) acc[a][b] = f32x4{0.f, 0.f, 0.f, 0.f};

  s16x8 bf[4][2], afX[4], afY[4];

  auto rdA = [&](s16x8* dst, int mfb, const ushort_t* Ab) {
    #pragma unroll
    for (int j = 0; j < 2; ++j)
      #pragma unroll
      for (int ks = 0; ks < 2; ++ks) {
        int row = wm + (mfb + j) * 16 + llo;
        int ch = (ks * 4 + lhi) ^ (row & 7);
        dst[j * 2 + ks] = *(const s16x8*)&Ab[row * 64 + ch * 8];
      }
  };
  auto rdB = [&](const ushort_t* Bb) {
    #pragma unroll
    for (int nf = 0; nf < 4; ++nf)
      #pragma unroll
      for (int ks = 0; ks < 2; ++ks) {
        int row = wn + nf * 16 + llo;
        int ch = (ks * 4 + lhi) ^ (row & 7);
        bf[nf][ks] = *(const s16x8*)&Bb[row * 64 + ch * 8];
      }
  };

#define MFMA_PHASE(P, AF)                                                        \
  __builtin_amdgcn_s_barrier();                                                  \
  asm volatile("s_waitcnt lgkmcnt(0)" ::: "memory");                             \
  __builtin_amdgcn_sched_barrier(0);                                             \
  __builtin_amdgcn_s_setprio(1);                                                 \
  _Pragma("unroll")                                                              \
  for (int j = 0; j < 2; ++j)                                                    \
    _Pragma("unroll")                                                            \
    for (int nf = 0; nf < 4; ++nf)                                               \
      _Pragma("unroll")                                                          \
      for (int ks = 0; ks < 2; ++ks)                                             \
        acc[(P) * 2 + j][nf] = __builtin_amdgcn_mfma_f32_16x16x32_bf16(          \
            AF[j * 2 + ks], bf[nf][ks], acc[(P) * 2 + j][nf], 0, 0, 0);          \
  __builtin_amdgcn_s_setprio(0);                                                 \
  __builtin_amdgcn_sched_barrier(0);                                             \
  __builtin_amdgcn_s_barrier();

  // ---- prologue: stage A[0], B[0], B[1]; wait A0+B0; preload afX(mf01 of A[0]) ----
  #pragma unroll
  for (int i = 0; i < 4; ++i) gload_lds16(pa0 + i * 512, &lds[i * 4096 + l0]);
  #pragma unroll
  for (int i = 0; i < 4; ++i) gload_lds16(pb0 + i * 512, &lds[32768 + i * 4096 + l0]);
  #pragma unroll
  for (int i = 0; i < 4; ++i) gload_lds16(pb0 + 65536 + i * 512, &lds[32768 + 16384 + i * 4096 + l0]);
  asm volatile("s_waitcnt vmcnt(4)" ::: "memory");   // A[0], B[0] complete; B[1] in flight
  __builtin_amdgcn_s_barrier();
  rdA(afX, 0, &lds[0]);

  for (int tt = 0; tt < KSTEPS; ++tt) {
    const ushort_t* Ab = &lds[(tt & 1) * 16384];
    const ushort_t* An = &lds[((tt + 1) & 1) * 16384];
    const ushort_t* Bb = &lds[32768 + (tt & 1) * 16384];
    ushort_t* dA  = &lds[((tt + 1) & 1) * 16384];
    ushort_t* dB2 = &lds[32768 + (tt & 1) * 16384];       // B[tt+2] parity == tt
    const ushort_t* sA  = pa0 + (size_t)(tt + 1) * 65536;
    const ushort_t* sB2 = pb0 + (size_t)(tt + 2) * 65536;
    bool pf1 = (tt + 1 < KSTEPS);
    bool pf2 = (tt + 2 < KSTEPS);

    // ---- p0: reads bf(B[tt]) + afY=mf23; issues A[tt+1] g0,g1; MFMA mf01(afX)
    rdB(Bb);
    rdA(afY, 2, Ab);
    if (pf1) {
      gload_lds16(sA,       dA + l0);
      gload_lds16(sA + 512, dA + 4096 + l0);
    }
    MFMA_PHASE(0, afX)

    // ---- p1: reads afX=mf45; issues A[tt+1] g2,g3; MFMA mf23(afY)
    rdA(afX, 4, Ab);
    if (pf1) {
      gload_lds16(sA + 1024, dA + 2 * 4096 + l0);
      gload_lds16(sA + 1536, dA + 3 * 4096 + l0);
    }
    MFMA_PHASE(1, afY)

    // ---- p2: reads afY=mf67; issues B[tt+2] g0,g1; MFMA mf45(afX)
    rdA(afY, 6, Ab);
    if (pf2) {
      gload_lds16(sB2,       dB2 + l0);
      gload_lds16(sB2 + 512, dB2 + 4096 + l0);
    }
    MFMA_PHASE(2, afX)

    // ---- p3: wait A[tt+1] ready; reads afX=mf01(A[tt+1]); issues B[tt+2] g2,g3; MFMA mf67(afY)
    if (pf1) {
      if (pf2) asm volatile("s_waitcnt vmcnt(2)" ::: "memory");  // leaves B[tt+2]g0,g1
      else     asm volatile("s_waitcnt vmcnt(0)" ::: "memory");  // TAIL: full drain (R10 fix)
      rdA(afX, 0, An);
    }
    if (pf2) {
      gload_lds16(sB2 + 1024, dB2 + 2 * 4096 + l0);
      gload_lds16(sB2 + 1536, dB2 + 3 * 4096 + l0);
    }
    MFMA_PHASE(3, afY)
  }
#undef MFMA_PHASE

  float* pbase = part + ((size_t)s << 20);
  #pragma unroll
  for (int mf = 0; mf < 8; ++mf)
    #pragma unroll
    for (int nf = 0; nf < 4; ++nf) {
      int n = n0 + wn + nf * 16 + llo;
      #pragma unroll
      for (int r2 = 0; r2 < 4; ++r2) {
        int m = m0 + wm + mf * 16 + lhi * 4 + r2; // C layout: col=lane&15, row=(lane>>4)*4+reg
        pbase[(size_t)m * 1024 + n] = acc[mf][nf][r2];
      }
    }
}

// ---------- reduce partials + bias + relu -> z1 ----------
__global__ __launch_bounds__(256) void k_red(const float* __restrict__ part,
                                             const float* __restrict__ bias,
                                             float* __restrict__ z1) {
  int idx = blockIdx.x * 256 + threadIdx.x;
  float a = bias[idx & 1023];
  #pragma unroll
  for (int s = 0; s < SPLITS; ++s) a += part[((size_t)s << 20) + idx];
  z1[idx] = fmaxf(a, 0.f);
}

// ---------- tiled fp32 SGEMM for top MLP: C=relu(A@W+b), 32x64 tile ----------
template<int K, int N>
__global__ __launch_bounds__(256) void k_sgemm(const float* __restrict__ A,
                                               const float* __restrict__ W,
                                               const float* __restrict__ bias,
                                               float* __restrict__ C) {
  __shared__ float As[16][34];
  __shared__ float Bs[16][68];
  int t = threadIdx.x;
  int m0 = blockIdx.x * 32, n0 = blockIdx.y * 64;
  int tx = t & 15, ty = t >> 4;
  float acc[2][4];
  #pragma unroll
  for (int j = 0; j < 2; ++j)
    #pragma unroll
    for (int q = 0; q < 4; ++q) acc[j][q] = 0.f;
  int ar = t >> 3, ak = (t & 7) * 2;
  int bk = t >> 4, bn = (t & 15) * 4;
  for (int k0 = 0; k0 < K; k0 += 16) {
    float2 av = *(const float2*)&A[(size_t)(m0 + ar) * K + k0 + ak];
    float4 bv = *(const float4*)&W[(size_t)(k0 + bk) * N + n0 + bn];
    __syncthreads();
    As[ak][ar] = av.x; As[ak + 1][ar] = av.y;
    *(float4*)&Bs[bk][bn] = bv;
    __syncthreads();
    #pragma unroll
    for (int k = 0; k < 16; ++k) {
      float2 a = *(const float2*)&As[k][ty * 2];
      float4 b = *(const float4*)&Bs[k][tx * 4];
      acc[0][0] = fmaf(a.x, b.x, acc[0][0]); acc[0][1] = fmaf(a.x, b.y, acc[0][1]);
      acc[0][2] = fmaf(a.x, b.z, acc[0][2]); acc[0][3] = fmaf(a.x, b.w, acc[0][3]);
      acc[1][0] = fmaf(a.y, b.x, acc[1][0]); acc[1][1] = fmaf(a.y, b.y, acc[1][1]);
      acc[1][2] = fmaf(a.y, b.z, acc[1][2]); acc[1][3] = fmaf(a.y, b.w, acc[1][3]);
    }
  }
  #pragma unroll
  for (int j = 0; j < 2; ++j) {
    int m = m0 + ty * 2 + j;
    float4 o;
    o.x = fmaxf(acc[j][0] + bias[n0 + tx * 4 + 0], 0.f);
    o.y = fmaxf(acc[j][1] + bias[n0 + tx * 4 + 1], 0.f);
    o.z = fmaxf(acc[j][2] + bias[n0 + tx * 4 + 2], 0.f);
    o.w = fmaxf(acc[j][3] + bias[n0 + tx * 4 + 3], 0.f);
    *(float4*)&C[(size_t)m * N + n0 + tx * 4] = o;
  }
}

// ---------- final layer: K=256 -> 1, wave reduction ----------
__global__ __launch_bounds__(256) void k_last(const float* __restrict__ z3,
                                              const float* __restrict__ w,
                                              const float* __restrict__ bias,
                                              float* __restrict__ out) {
  int t = threadIdx.x, l = t & 63, wv = t >> 6;
  int m = blockIdx.x * 4 + wv;
  float s = 0.f;
  #pragma unroll
  for (int c = 0; c < 4; ++c) s = fmaf(z3[(size_t)m * 256 + c * 64 + l], w[c * 64 + l], s);
  #pragma unroll
  for (int off = 32; off; off >>= 1) s += __shfl_down(s, off, 64);
  if (l == 0) out[m] = s + bias[0];
}

// ---------- fallback path (small workspace): fp32 fused-gen GEMM ----------
__global__ __launch_bounds__(256) void k_z1init(const float* __restrict__ bias, float* __restrict__ z1) {
  int idx = blockIdx.x * 256 + threadIdx.x;
  z1[idx] = bias[idx & 1023];
}
__global__ __launch_bounds__(256) void k_relu(float* __restrict__ z1) {
  int idx = blockIdx.x * 256 + threadIdx.x;
  z1[idx] = fmaxf(z1[idx], 0.f);
}
constexpr int FB_S = 8;
__global__ __launch_bounds__(256) void k_fbgemm(const float* __restrict__ xT,
                                                const int* __restrict__ iu,
                                                const float* __restrict__ tw0,
                                                float* __restrict__ z1) {
  __shared__ float zs[32 * 64];
  __shared__ float wsb[32 * 64];
  int t = threadIdx.x;
  int m0 = blockIdx.x * 64, n0 = blockIdx.y * 64, s = blockIdx.z;
  int kch = (K1 + FB_S - 1) / FB_S;
  int k0 = s * kch, kend = min(k0 + kch, K1);
  float acc[16];
  #pragma unroll
  for (int q = 0; q < 16; ++q) acc[q] = 0.f;
  int mm = t & 63, ng = t >> 6;
  for (int kk = k0; kk < kend; kk += 32) {
    __syncthreads();
    for (int sl = t; sl < 2048; sl += 256) {
      int kloc = sl >> 6, v6 = sl & 63;
      int k = kk + kloc;
      float zv = 0.f, wv = 0.f;
      if (k < kend) {
        int ij = iu[k];
        int i = ij & 0xFFFF, j = ij >> 16;
        zv = xT[(size_t)i * B_ + m0 + v6] * xT[(size_t)j * B_ + m0 + v6];
        wv = tw0[(size_t)k * 1024 + n0 + v6];
      }
      zs[kloc * 64 + v6] = zv;
      wsb[kloc * 64 + v6] = wv;
    }
    __syncthreads();
    #pragma unroll 4
    for (int kloc = 0; kloc < 32; ++kloc) {
      float zv = zs[kloc * 64 + mm];
      #pragma unroll
      for (int q = 0; q < 16; ++q)
        acc[q] = fmaf(zv, wsb[kloc * 64 + ng * 16 + q], acc[q]);
    }
  }
  #pragma unroll
  for (int q = 0; q < 16; ++q)
    atomicAdd(&z1[(size_t)(m0 + mm) * 1024 + n0 + ng * 16 + q], acc[q]);
}

extern "C" void kernel_launch(void* const* d_in, const int* in_sizes, int n_in,
                              void* d_out, int out_size, void* d_ws, size_t ws_size,
                              hipStream_t stream) {
  const float* dense  = (const float*)d_in[0];
  const int*   sparse = (const int*)  d_in[1];
  const float* emb    = (const float*)d_in[2];
  const float* bw0 = (const float*)d_in[3];  const float* bb0 = (const float*)d_in[4];
  const float* bw1 = (const float*)d_in[5];  const float* bb1 = (const float*)d_in[6];
  const float* bw2 = (const float*)d_in[7];  const float* bb2 = (const float*)d_in[8];
  const float* bw3 = (const float*)d_in[9];  const float* bb3 = (const float*)d_in[10];
  const float* tw0 = (const float*)d_in[11]; const float* tb0 = (const float*)d_in[12];
  const float* tw1 = (const float*)d_in[13]; const float* tb1 = (const float*)d_in[14];
  const float* tw2 = (const float*)d_in[15]; const float* tb2 = (const float*)d_in[16];
  const float* tw3 = (const float*)d_in[17]; const float* tb3 = (const float*)d_in[18];
  float* out = (float*)d_out;

  char* ws = (char*)d_ws;
  size_t off = 0;
  auto alloc = [&](size_t bytes) -> char* {
    char* p = ws + off;
    off = (off + bytes + 255) & ~(size_t)255;
    return p;
  };
  float* xT = (float*)alloc((size_t)434 * 1024 * 4);
  int*   iu = (int*)  alloc((size_t)Kp * 4);
  float* z1 = (float*)alloc((size_t)1024 * 1024 * 4);
  float* z2 = (float*)alloc((size_t)1024 * 512 * 4);
  float* z3 = (float*)alloc((size_t)1024 * 256 * 4);
  ushort_t* Z    = (ushort_t*)alloc((size_t)1024 * Kp * 2);
  ushort_t* WT   = (ushort_t*)alloc((size_t)1024 * Kp * 2);
  float*    part = (float*)   alloc((size_t)SPLITS * 1024 * 1024 * 4);
  bool big = (off <= ws_size);

  // big path: 6616 blocks (incl. 5888 wt-convert); fallback: 728 (no WT writes)
  int preGrid = big ? 6616 : 728;
  k_pre<<<preGrid, 256, 0, stream>>>(dense, sparse, emb, bw0, bb0, bw1, bb1,
                                     bw2, bb2, bw3, bb3, tw0, iu, xT, WT);

  if (big) {
    k_genz<<<2944, 256, 0, stream>>>(xT, iu, Z);
    k_gemm<<<256, 512, 0, stream>>>(Z, WT, part);
    k_red<<<4096, 256, 0, stream>>>(part, tb0, z1);
  } else {
    k_z1init<<<4096, 256, 0, stream>>>(tb0, z1);
    k_fbgemm<<<dim3(16, 16, FB_S), 256, 0, stream>>>(xT, iu, tw0, z1);
    k_relu<<<4096, 256, 0, stream>>>(z1);
  }

  k_sgemm<1024, 512><<<dim3(32, 8), 256, 0, stream>>>(z1, tw1, tb1, z2);
  k_sgemm<512, 256><<<dim3(32, 4), 256, 0, stream>>>(z2, tw2, tb2, z3);
  k_last<<<256, 256, 0, stream>>>(z3, tw3, tb3, out);
}